// Round 1
// baseline (314.546 us; speedup 1.0000x reference)
//
#include <hip/hip_runtime.h>
#include <math.h>

// Detector loss: N=65536 samples, G=7 (49 cells), A=3 anchors, C=2 classes.
// bbox_ : (N,15,7,7) predictions, channel 5a+0 = objectness(a), 5a+1..5a+4 = x,y,w,h
// bbox  : (N, 5,7,7) GT,          channel 0 = prob map,        1..4       = x,y,w,h
// cls_  : (N,2) logits; cls : (N,) labels in {1,2}
// out   : scalar fp32
//
// Strategy: line granularity forces ~full-sample fetch anyway (cell-m scatters hit
// 16 distinct channels), so stream the WHOLE sample with 16 coalesced 256B dword
// loads (all independent -> 4KB in flight/wave), park it in per-wave LDS, and turn
// every data-dependent access into an LDS broadcast read. No dependent global
// loads, no shuffle broadcasts.

static constexpr int GG_ = 49;
static constexpr int PRD = 15 * GG_; // 735 dwords / pred sample
static constexpr int GTD = 5  * GG_; // 245 dwords / gt sample

__global__ void zero_kernel(float* out) { if (threadIdx.x == 0) out[0] = 0.0f; }

__global__ __launch_bounds__(256) void loss_kernel(
    const float* __restrict__ pr_all,     // bbox_
    const float* __restrict__ cls_logits, // cls_
    const float* __restrict__ gt_all,     // bbox
    const int*   __restrict__ cls_lbl,    // cls
    float* __restrict__ out, int N)
{
    const int lane   = threadIdx.x & 63;
    const int wslot  = threadIdx.x >> 6;
    const int wid    = blockIdx.x * (blockDim.x >> 6) + wslot;
    const int nwaves = gridDim.x * (blockDim.x >> 6);
    const float invG   = 1.0f / 7.0f;
    const float invN   = 1.0f / (float)N;
    const float invN49 = 1.0f / ((float)N * 49.0f);

    // per-wave sample buffers (4 waves/block, 16 KiB total -> 8 blocks/CU fits 160K)
    __shared__ float lds_pr[4][768];
    __shared__ float lds_gt[4][256];
    float* __restrict__ Lpr = lds_pr[wslot];
    float* __restrict__ Lgt = lds_gt[wslot];

    float acc = 0.0f;

    for (int n = wid; n < N; n += nwaves) {
        const float* pr = pr_all + (size_t)n * PRD;
        const float* gt = gt_all + (size_t)n * GTD;

        // ---- 1) stream the whole sample: 16 independent coalesced 256B loads ----
        float p[12];
        #pragma unroll
        for (int k = 0; k < 12; k++) {
            int d = lane + 64 * k;
            if (d > PRD - 1) d = PRD - 1;      // tail clamp (k=11 only; others fold)
            p[k] = pr[d];
        }
        float g[4];
        #pragma unroll
        for (int k = 0; k < 4; k++) {
            int d = lane + 64 * k;
            if (d > GTD - 1) d = GTD - 1;      // tail clamp (k=3 only)
            g[k] = gt[d];
        }
        // wave-uniform scalar-ish loads for CE — issue early, independent
        const float x0 = cls_logits[2 * n];
        const float x1 = cls_logits[2 * n + 1];
        const int   c  = cls_lbl[n] - 1;

        // ---- 2) park sample in LDS (per-wave buffer, wave-synchronous use) ----
        #pragma unroll
        for (int k = 0; k < 12; k++) Lpr[lane + 64 * k] = p[k];
        #pragma unroll
        for (int k = 0; k < 4;  k++) Lgt[lane + 64 * k] = g[k];
        // drain DS writes before dependent reads; memory clobber also pins ordering
        asm volatile("s_waitcnt lgkmcnt(0)" ::: "memory");

        // ---- 3) GT prob map argmax (min-index tie-break); t = per-cell gt prob ----
        const float t = (lane < GG_) ? g[0] : -1.0f;  // sentinel loses (probs>=0.01)
        float v = t; int idx = lane;
        #pragma unroll
        for (int off = 32; off; off >>= 1) {
            float v2 = __shfl_xor(v, off);
            int   i2 = __shfl_xor(idx, off);
            if (v2 > v || (v2 == v && i2 < idx)) { v = v2; idx = i2; }
        }
        const int m  = idx;                 // wave-uniform
        const int mi = m / 7, mj = m - mi * 7;
        const float jf = (float)mj, if_ = (float)mi;

        // ---- 4) cell-m values via wave-uniform LDS broadcast reads ----
        const float g1 = Lgt[ 49 + m];      // GT x
        const float g2 = Lgt[ 98 + m];      // GT y
        const float g3 = Lgt[147 + m];      // GT w
        const float g4 = Lgt[196 + m];      // GT h

        const float tx  = (g1 + jf) * invG;
        const float ty  = (g2 + if_) * invG;
        const float tx1 = tx - g3 * 0.5f, tx2 = tx + g3 * 0.5f;
        const float ty1 = ty - g4 * 0.5f, ty2 = ty + g4 * 0.5f;
        const float tarea = (tx2 - tx1) * (ty2 - ty1);

        // ---- 5) IoU argmax over anchors (uniform on all lanes, no shuffles) ----
        int best = 0; float bestIoU = -1.0f;
        float px = 0.f, py = 0.f, pw = 0.f, ph = 0.f;
        #pragma unroll
        for (int a = 0; a < 3; a++) {
            float c1 = Lpr[(5 * a + 1) * GG_ + m];
            float c2 = Lpr[(5 * a + 2) * GG_ + m];
            float c3 = Lpr[(5 * a + 3) * GG_ + m];
            float c4 = Lpr[(5 * a + 4) * GG_ + m];
            float ax  = (c1 + jf) * invG;
            float ay  = (c2 + if_) * invG;
            float ax1 = ax - c3 * 0.5f, ax2 = ax + c3 * 0.5f;
            float ay1 = ay - c4 * 0.5f, ay2 = ay + c4 * 0.5f;
            float iw = fminf(ax2, tx2) - fmaxf(ax1, tx1); iw = fmaxf(iw, 0.0f);
            float ih = fminf(ay2, ty2) - fmaxf(ay1, ty1); ih = fmaxf(ih, 0.0f);
            float inter = iw * ih;
            float uni   = (ax2 - ax1) * (ay2 - ay1) + tarea - inter;
            float iou   = inter / (uni + 1e-9f);
            if (iou > bestIoU) { bestIoU = iou; best = a; px = c1; py = c2; pw = c3; ph = c4; }
        }

        // ---- 6) prob_loss: -log(1-p) over the 3 objectness channels, straight
        //         from staged regs. Objectness dwords: [0,49) [245,294) [490,539)
        //         -> regs k=0,3,4,7,8 with contiguous lane ranges. ----
        float s = 0.0f;
        if (lane < 49) s -= __logf(1.0f - p[0]);   // d = l        in [0,49)
        if (lane >= 53) s -= __logf(1.0f - p[3]);  // d = l + 192  in [245,255]
        if (lane < 38) s -= __logf(1.0f - p[4]);   // d = l + 256  in [256,293]
        if (lane >= 42) s -= __logf(1.0f - p[7]);  // d = l + 448  in [490,511]
        if (lane < 27) s -= __logf(1.0f - p[8]);   // d = l + 512  in [512,538]

        // best-channel correction: target = gt prob map for channel best
        if (lane < GG_) {
            float pb = Lpr[245 * best + lane];     // contiguous -> 2-way alias, free
            s -= t * (__logf(pb) - __logf(1.0f - pb));
        }
        acc += s * invN49;

        // ---- 7) coord (BCE sum) + size (log-diff L1 sum) + CE mean ----
        if (lane == 0) {
            float coord = -(g1 * __logf(px) + (1.0f - g1) * __logf(1.0f - px))
                          -(g2 * __logf(py) + (1.0f - g2) * __logf(1.0f - py));
            float size  = fabsf(__logf(pw) - __logf(g3))
                        + fabsf(__logf(ph) - __logf(g4));
            float mx  = fmaxf(x0, x1);
            float lse = mx + __logf(__expf(x0 - mx) + __expf(x1 - mx));
            float lp  = ((c == 0) ? x0 : x1) - lse;
            acc += coord + size - lp * invN;
        }
    }

    // ---- block reduction, one atomic per block ----
    #pragma unroll
    for (int off = 32; off; off >>= 1) acc += __shfl_xor(acc, off);
    __shared__ float wsum[4];
    if (lane == 0) wsum[wslot] = acc;
    __syncthreads();
    if (threadIdx.x == 0) {
        atomicAdd(out, wsum[0] + wsum[1] + wsum[2] + wsum[3]);
    }
}

extern "C" void kernel_launch(void* const* d_in, const int* in_sizes, int n_in,
                              void* d_out, int out_size, void* d_ws, size_t ws_size,
                              hipStream_t stream) {
    const float* bbox_p = (const float*)d_in[0];   // (N,15,7,7)
    const float* cls_p  = (const float*)d_in[1];   // (N,2)
    const float* bbox_g = (const float*)d_in[2];   // (N,5,7,7)
    const int*   cls_l  = (const int*)d_in[3];     // (N,)
    float* out = (float*)d_out;
    const int N = in_sizes[3];

    hipLaunchKernelGGL(zero_kernel, dim3(1), dim3(64), 0, stream, out);
    // 2048 blocks x 4 waves = 8192 waves, 8 samples/wave; 2048 atomics total.
    hipLaunchKernelGGL(loss_kernel, dim3(2048), dim3(256), 0, stream,
                       bbox_p, cls_p, bbox_g, cls_l, out, N);
}